// Round 1
// baseline (202.697 us; speedup 1.0000x reference)
//
#include <hip/hip_runtime.h>

// BurstSnn: 32-step burst-encoder + 2-layer LIF SNN, B=16384, D=187, H=50, C=5.
// Mapping: one wave per batch element (4 waves = 256 threads per block).
//  - Encoder state (r, th) lives in registers: 3 dims per lane (64*3 >= 187).
//  - Spike masks via __ballot -> wave-uniform u64; layer-1 current computed by
//    iterating set bits (sparse: ~2-3 spikes/dim TOTAL over all 32 steps) and
//    gathering W1^T columns from LDS. Lanes 0..49 hold the 50 hidden LIF states.
//  - Layer 2 same trick with W2^T; lanes 0..4 hold the 5 output LIF states.
// Counts output is exact (encoder ops replicate numpy's fp32 sequence 1:1).

constexpr int D = 187;
constexpr int H = 50;
constexpr int C = 5;
constexpr int T = 32;

__global__ __launch_bounds__(256, 4)
void burst_snn_kernel(const float* __restrict__ x,
                      const float* __restrict__ W1,
                      const float* __restrict__ W2,
                      float* __restrict__ out, int B) {
    // W1^T: Wt1[d*H + h] = W1[h*D + d]; +16 zero pad so lanes 50..63 read zeros at d=186
    __shared__ float Wt1[D * H + 16];
    __shared__ float Wt2[320]; // W2^T: Wt2[h*C + c] = W2[c*H + h]; padded (max idx 49*5+63=308)

    const int tid = threadIdx.x;
    for (int i = tid; i < D * H; i += 256) {
        int h = i / D;
        int d = i - h * D;
        Wt1[d * H + h] = W1[i];
    }
    if (tid < 16) Wt1[D * H + tid] = 0.f;
    for (int i = tid; i < H * C; i += 256) {
        int c = i / H;
        int h = i - c * H;
        Wt2[h * C + c] = W2[i];
    }
    if (tid < 320 - H * C) Wt2[H * C + tid] = 0.f;
    __syncthreads();

    const int lane = tid & 63;
    const int b = blockIdx.x * 4 + (tid >> 6);
    const bool active = b < B;

    // Encoder registers: dims lane, lane+64, lane+128 (last valid only for lane<59)
    float r0 = 0.f, r1 = 0.f, r2 = 0.f;
    if (active) {
        const float* xb = x + (size_t)b * D;
        r0 = xb[lane];
        r1 = xb[64 + lane];
        if (lane < D - 128) r2 = xb[128 + lane];
    }
    float th0 = 0.125f, th1 = 0.125f, th2 = 0.125f;
    float mem1 = 0.f;  // hidden LIF state, lane h (lanes 0..49 meaningful)
    float mem2 = 0.f;  // output LIF state, lane c (lanes 0..4 meaningful)
    int cnt = 0;

    float* outSpk = out;                          // [T][B][C]
    float* outCnt = out + (size_t)T * B * C;      // [B]

    for (int t = 0; t < T; ++t) {
        // --- burst encoder (exact fp32 sequence: compare, subtract, double/reset)
        bool s0 = r0 >= th0;
        bool s1 = r1 >= th1;
        bool s2 = r2 >= th2;
        r0 -= s0 ? th0 : 0.f; th0 = s0 ? th0 + th0 : 0.125f;
        r1 -= s1 ? th1 : 0.f; th1 = s1 ? th1 + th1 : 0.125f;
        r2 -= s2 ? th2 : 0.f; th2 = s2 ? th2 + th2 : 0.125f;
        cnt += (int)s0 + (int)s1 + (int)s2;

        unsigned long long m0 = __ballot(s0);
        unsigned long long m1 = __ballot(s1);
        unsigned long long m2 = __ballot(s2);

        // --- layer 1 current: sparse gather of W1^T rows (wave-uniform loops)
        float cur1 = 0.f;
        while (m0) { int d = __builtin_ctzll(m0); m0 &= m0 - 1; cur1 += Wt1[d * H + lane]; }
        while (m1) { int d = __builtin_ctzll(m1); m1 &= m1 - 1; cur1 += Wt1[(d + 64) * H + lane]; }
        while (m2) { int d = __builtin_ctzll(m2); m2 &= m2 - 1; cur1 += Wt1[(d + 128) * H + lane]; }

        mem1 = 0.9f * mem1 + cur1;
        bool sp1 = (mem1 - 1.0f > 0.f) && (lane < H);
        mem1 -= sp1 ? 1.0f : 0.f;

        // --- layer 2 current: sparse gather of W2^T rows
        unsigned long long mh = __ballot(sp1);
        float cur2 = 0.f;
        while (mh) { int h = __builtin_ctzll(mh); mh &= mh - 1; cur2 += Wt2[h * C + lane]; }

        mem2 = 0.9f * mem2 + cur2;
        bool sp2 = (mem2 - 1.0f > 0.f);
        mem2 -= sp2 ? 1.0f : 0.f;

        if (active && lane < C)
            outSpk[(size_t)t * B * C + (size_t)b * C + lane] = sp2 ? 1.0f : 0.0f;
    }

    // --- reduce spike count across the wave, write counts[b]
    for (int o = 32; o; o >>= 1) cnt += __shfl_xor(cnt, o, 64);
    if (active && lane == 0) outCnt[b] = (float)cnt;
}

extern "C" void kernel_launch(void* const* d_in, const int* in_sizes, int n_in,
                              void* d_out, int out_size, void* d_ws, size_t ws_size,
                              hipStream_t stream) {
    const float* x  = (const float*)d_in[0];
    const float* W1 = (const float*)d_in[1];
    const float* W2 = (const float*)d_in[2];
    float* out = (float*)d_out;
    const int B = in_sizes[0] / D;
    const int blocks = (B + 3) / 4;
    burst_snn_kernel<<<blocks, 256, 0, stream>>>(x, W1, W2, out, B);
}

// Round 2
// 175.538 us; speedup vs baseline: 1.1547x; 1.1547x over previous
//
#include <hip/hip_runtime.h>

// BurstSnn: 32-step burst-encoder + 2-layer LIF SNN, B=16384, D=187, H=50, C=5.
// Mapping: one wave per batch element; 16 waves (1024 threads) per block share
// ONE LDS copy of W1^T/W2^T. LDS=38KB -> wave-cap-bound: 2 blocks/CU = 32
// waves/CU = 100% occupancy (VGPR=52 fits 8 waves/SIMD).
//  - Encoder state (r, th) in registers: 3 dims per lane (64*3 >= 187).
//  - Spike masks via __ballot -> wave-uniform u64; layer-1 current = sparse
//    gather of W1^T rows from LDS, iterating set bits in increasing-d order
//    (identical fp32 summation order to the verified R0 kernel: absmax 0.0).
//  - Lanes 0..49 hold hidden LIF states; lanes 0..4 hold output LIF states.

constexpr int D = 187;
constexpr int H = 50;
constexpr int C = 5;
constexpr int T = 32;
constexpr int WAVES_PER_BLOCK = 16;

__global__ __launch_bounds__(1024, 8)
void burst_snn_kernel(const float* __restrict__ x,
                      const float* __restrict__ W1,
                      const float* __restrict__ W2,
                      float* __restrict__ out, int B) {
    // W1^T: Wt1[d*H + h] = W1[h*D + d]; +16 zero pad so lanes 50..63 read zeros at d=186
    __shared__ float Wt1[D * H + 16];
    __shared__ float Wt2[320]; // W2^T: Wt2[h*C + c] = W2[c*H + h]; padded (max idx 49*5+63=308)

    const int tid = threadIdx.x;
    for (int i = tid; i < D * H; i += 1024) {
        int h = i / D;
        int d = i - h * D;
        Wt1[d * H + h] = W1[i];
    }
    if (tid < 16) Wt1[D * H + tid] = 0.f;
    if (tid < H * C) {
        int c = tid / H;
        int h = tid - c * H;
        Wt2[h * C + c] = W2[tid];
    }
    if (tid < 320 - H * C) Wt2[H * C + tid] = 0.f;
    __syncthreads();

    const int lane = tid & 63;
    const int b = blockIdx.x * WAVES_PER_BLOCK + (tid >> 6);
    const bool active = b < B;

    // Encoder registers: dims lane, lane+64, lane+128 (last valid only for lane<59)
    float r0 = 0.f, r1 = 0.f, r2 = 0.f;
    if (active) {
        const float* xb = x + (size_t)b * D;
        r0 = xb[lane];
        r1 = xb[64 + lane];
        if (lane < D - 128) r2 = xb[128 + lane];
    }
    float th0 = 0.125f, th1 = 0.125f, th2 = 0.125f;
    float mem1 = 0.f;  // hidden LIF state, lane h (lanes 0..49 meaningful)
    float mem2 = 0.f;  // output LIF state, lane c (lanes 0..4 meaningful)
    int cnt = 0;

    float* outSpk = out;                          // [T][B][C]
    float* outCnt = out + (size_t)T * B * C;      // [B]

    for (int t = 0; t < T; ++t) {
        // --- burst encoder (exact fp32 sequence: compare, subtract, double/reset)
        bool s0 = r0 >= th0;
        bool s1 = r1 >= th1;
        bool s2 = r2 >= th2;
        r0 -= s0 ? th0 : 0.f; th0 = s0 ? th0 + th0 : 0.125f;
        r1 -= s1 ? th1 : 0.f; th1 = s1 ? th1 + th1 : 0.125f;
        r2 -= s2 ? th2 : 0.f; th2 = s2 ? th2 + th2 : 0.125f;
        cnt += (int)s0 + (int)s1 + (int)s2;

        unsigned long long m0 = __ballot(s0);
        unsigned long long m1 = __ballot(s1);
        unsigned long long m2 = __ballot(s2);

        // --- layer 1 current: sparse gather of W1^T rows (wave-uniform loops)
        float cur1 = 0.f;
        while (m0) { int d = __builtin_ctzll(m0); m0 &= m0 - 1; cur1 += Wt1[d * H + lane]; }
        while (m1) { int d = __builtin_ctzll(m1); m1 &= m1 - 1; cur1 += Wt1[(d + 64) * H + lane]; }
        while (m2) { int d = __builtin_ctzll(m2); m2 &= m2 - 1; cur1 += Wt1[(d + 128) * H + lane]; }

        mem1 = 0.9f * mem1 + cur1;
        bool sp1 = (mem1 - 1.0f > 0.f) && (lane < H);
        mem1 -= sp1 ? 1.0f : 0.f;

        // --- layer 2 current: sparse gather of W2^T rows
        unsigned long long mh = __ballot(sp1);
        float cur2 = 0.f;
        while (mh) { int h = __builtin_ctzll(mh); mh &= mh - 1; cur2 += Wt2[h * C + lane]; }

        mem2 = 0.9f * mem2 + cur2;
        bool sp2 = (mem2 - 1.0f > 0.f);
        mem2 -= sp2 ? 1.0f : 0.f;

        if (active && lane < C)
            outSpk[(size_t)t * B * C + (size_t)b * C + lane] = sp2 ? 1.0f : 0.0f;
    }

    // --- reduce spike count across the wave, write counts[b]
    for (int o = 32; o; o >>= 1) cnt += __shfl_xor(cnt, o, 64);
    if (active && lane == 0) outCnt[b] = (float)cnt;
}

extern "C" void kernel_launch(void* const* d_in, const int* in_sizes, int n_in,
                              void* d_out, int out_size, void* d_ws, size_t ws_size,
                              hipStream_t stream) {
    const float* x  = (const float*)d_in[0];
    const float* W1 = (const float*)d_in[1];
    const float* W2 = (const float*)d_in[2];
    float* out = (float*)d_out;
    const int B = in_sizes[0] / D;
    const int blocks = (B + WAVES_PER_BLOCK - 1) / WAVES_PER_BLOCK;
    burst_snn_kernel<<<blocks, 1024, 0, stream>>>(x, W1, W2, out, B);
}

// Round 3
// 175.326 us; speedup vs baseline: 1.1561x; 1.0012x over previous
//
#include <hip/hip_runtime.h>

// BurstSnn: 32-step burst-encoder + 2-layer LIF SNN, B=16384, D=187, H=50, C=5.
// One wave per batch element; 16 waves (1024 threads) per block share one LDS
// copy of W1^T/W2^T (wave-cap occupancy: 2 blocks/CU = 32 waves/CU).
// R2 change: spike masks are forced into SGPRs via readfirstlane so the
// bit-scan gather loops run on the SALU pipe (s_ff1_i64/s_and_b64/s_cbranch)
// with only {v_add addr, ds_read_b32, v_add_f32} on the vector side.
// Summation order identical to the verified R0/R1 kernels (absmax 0.0).

constexpr int D = 187;
constexpr int H = 50;
constexpr int C = 5;
constexpr int T = 32;
constexpr int WAVES_PER_BLOCK = 16;

__device__ __forceinline__ unsigned long long uniform_u64(unsigned long long m) {
    unsigned int lo = __builtin_amdgcn_readfirstlane((unsigned int)m);
    unsigned int hi = __builtin_amdgcn_readfirstlane((unsigned int)(m >> 32));
    return ((unsigned long long)hi << 32) | lo;
}

__global__ __launch_bounds__(1024, 8)
void burst_snn_kernel(const float* __restrict__ x,
                      const float* __restrict__ W1,
                      const float* __restrict__ W2,
                      float* __restrict__ out, int B) {
    // W1^T: Wt1[d*H + h] = W1[h*D + d]; +16 zero pad so lanes 50..63 read zeros at d=186
    __shared__ float Wt1[D * H + 16];
    __shared__ float Wt2[320]; // W2^T: Wt2[h*C + c] = W2[c*H + h]; padded (max idx 49*5+63=308)

    const int tid = threadIdx.x;
    for (int i = tid; i < D * H; i += 1024) {
        int h = i / D;
        int d = i - h * D;
        Wt1[d * H + h] = W1[i];
    }
    if (tid < 16) Wt1[D * H + tid] = 0.f;
    if (tid < H * C) {
        int c = tid / H;
        int h = tid - c * H;
        Wt2[h * C + c] = W2[tid];
    }
    if (tid < 320 - H * C) Wt2[H * C + tid] = 0.f;
    __syncthreads();

    const int lane = tid & 63;
    const int b = blockIdx.x * WAVES_PER_BLOCK + (tid >> 6);
    const bool active = b < B;

    // Per-lane base pointers (hoisted): gather loops add only a uniform row offset.
    const float* Wt1L = Wt1 + lane;   // + d*H (uniform)
    const float* Wt2L = Wt2 + lane;   // + h*C (uniform)

    // Encoder registers: dims lane, lane+64, lane+128 (last valid only for lane<59)
    float r0 = 0.f, r1 = 0.f, r2 = 0.f;
    if (active) {
        const float* xb = x + (size_t)b * D;
        r0 = xb[lane];
        r1 = xb[64 + lane];
        if (lane < D - 128) r2 = xb[128 + lane];
    }
    float th0 = 0.125f, th1 = 0.125f, th2 = 0.125f;
    float mem1 = 0.f;  // hidden LIF state, lane h (lanes 0..49 meaningful)
    float mem2 = 0.f;  // output LIF state, lane c (lanes 0..4 meaningful)
    int cnt = 0;

    float* outSpk = out;                          // [T][B][C]
    float* outCnt = out + (size_t)T * B * C;      // [B]

    for (int t = 0; t < T; ++t) {
        // --- burst encoder (exact fp32 sequence: compare, subtract, double/reset)
        bool s0 = r0 >= th0;
        bool s1 = r1 >= th1;
        bool s2 = r2 >= th2;
        r0 -= s0 ? th0 : 0.f; th0 = s0 ? th0 + th0 : 0.125f;
        r1 -= s1 ? th1 : 0.f; th1 = s1 ? th1 + th1 : 0.125f;
        r2 -= s2 ? th2 : 0.f; th2 = s2 ? th2 + th2 : 0.125f;
        cnt += (int)s0 + (int)s1 + (int)s2;

        unsigned long long m0 = uniform_u64(__ballot(s0));
        unsigned long long m1 = uniform_u64(__ballot(s1));
        unsigned long long m2 = uniform_u64(__ballot(s2));

        // --- layer 1 current: sparse gather of W1^T rows (scalar bit-scan loops)
        float cur1 = 0.f;
        while (m0) { int d = (int)__builtin_ctzll(m0); m0 &= m0 - 1; cur1 += Wt1L[d * H]; }
        while (m1) { int d = (int)__builtin_ctzll(m1); m1 &= m1 - 1; cur1 += Wt1L[(d + 64) * H]; }
        while (m2) { int d = (int)__builtin_ctzll(m2); m2 &= m2 - 1; cur1 += Wt1L[(d + 128) * H]; }

        mem1 = 0.9f * mem1 + cur1;
        bool sp1 = (mem1 - 1.0f > 0.f) && (lane < H);
        mem1 -= sp1 ? 1.0f : 0.f;

        // --- layer 2 current: sparse gather of W2^T rows
        unsigned long long mh = uniform_u64(__ballot(sp1));
        float cur2 = 0.f;
        while (mh) { int h = (int)__builtin_ctzll(mh); mh &= mh - 1; cur2 += Wt2L[h * C]; }

        mem2 = 0.9f * mem2 + cur2;
        bool sp2 = (mem2 - 1.0f > 0.f);
        mem2 -= sp2 ? 1.0f : 0.f;

        if (active && lane < C)
            outSpk[(size_t)t * B * C + (size_t)b * C + lane] = sp2 ? 1.0f : 0.0f;
    }

    // --- reduce spike count across the wave, write counts[b]
    for (int o = 32; o; o >>= 1) cnt += __shfl_xor(cnt, o, 64);
    if (active && lane == 0) outCnt[b] = (float)cnt;
}

extern "C" void kernel_launch(void* const* d_in, const int* in_sizes, int n_in,
                              void* d_out, int out_size, void* d_ws, size_t ws_size,
                              hipStream_t stream) {
    const float* x  = (const float*)d_in[0];
    const float* W1 = (const float*)d_in[1];
    const float* W2 = (const float*)d_in[2];
    float* out = (float*)d_out;
    const int B = in_sizes[0] / D;
    const int blocks = (B + WAVES_PER_BLOCK - 1) / WAVES_PER_BLOCK;
    burst_snn_kernel<<<blocks, 1024, 0, stream>>>(x, W1, W2, out, B);
}